// Round 12
// baseline (1192.739 us; speedup 1.0000x reference)
//
#include <hip/hip_runtime.h>

#define NBATCH 256
#define SLEN   2048
#define NTAG   64
#define BOS_T  1
#define EOS_T  2

#define BT_BYTES   131072
#define RING_ROWS  64
#define RING_BYTES (RING_ROWS * NTAG * 4)      // 16 KB
#define FLAG_OFF   (BT_BYTES + RING_BYTES)     // 64 x u32
#define PROG_OFF   (FLAG_OFF + 256)            // 8 x u32
#define LDS_BYTES  (PROG_OFF + 32)             // 147744 < 160 KB

__device__ __forceinline__ float lane_bcast(float v, int lane) {
    return __uint_as_float(__builtin_amdgcn_readlane(__float_as_uint(v), lane));
}

#define TAGS_ALL(X) \
  X(0)  X(1)  X(2)  X(3)  X(4)  X(5)  X(6)  X(7)  \
  X(8)  X(9)  X(10) X(11) X(12) X(13) X(14) X(15) \
  X(16) X(17) X(18) X(19) X(20) X(21) X(22) X(23) \
  X(24) X(25) X(26) X(27) X(28) X(29) X(30) X(31) \
  X(32) X(33) X(34) X(35) X(36) X(37) X(38) X(39) \
  X(40) X(41) X(42) X(43) X(44) X(45) X(46) X(47) \
  X(48) X(49) X(50) X(51) X(52) X(53) X(54) X(55) \
  X(56) X(57) X(58) X(59) X(60) X(61) X(62) X(63)

#define DECL_TC(p) float tc##p = trans[(p) * NTAG + lane];
#define KEEP_TC(p) asm volatile("" : "+v"(tc##p));
#define CAND(p)    float cd##p = lane_bcast(bcv, p) + tc##p;

#define FM3(x, y, z) fmaxf(fmaxf((x), (y)), (z))

// tournament leaf: candidates pa<pb; >= keeps the lower index on ties
#define LEAF(i, pa, pb) \
  float va##i; int ia##i; { bool g_ = (cd##pa >= cd##pb); \
    va##i = g_ ? cd##pa : cd##pb; ia##i = g_ ? (pa) : (pb); }
#define MRG(vo, io, vA, iA, vB, iB) \
  float vo; int io; { bool g_ = ((vA) >= (vB)); \
    vo = g_ ? (vA) : (vB); io = g_ ? (iA) : (iB); }

// Producer/consumer split: wave 0 runs the value-only recursion with NO
// barrier and NO LDS read on its critical path (alpha in registers,
// readlane broadcast); it publishes alpha rows to an LDS ring. Waves 1-7
// recompute the exact argmax per step (lagged) and write bt. r8-r11 showed
// the per-step barrier+LDS latency chain (~800 cyc) dominates regardless
// of inner work; this removes it from the serial path entirely.
__global__ __launch_bounds__(512)
__attribute__((amdgpu_waves_per_eu(2, 2)))
void crf_viterbi(const float* __restrict__ emissions,  // [B,S,C]
                 const float* __restrict__ mask,       // [B,S]
                 const float* __restrict__ trans,      // [C,C]
                 int* __restrict__ out)                // [B,S] int32 tags
{
    extern __shared__ unsigned char lds[];
    unsigned char* bt = lds;                          // [S-1][64]
    float* ring = (float*)(lds + BT_BYTES);           // [64][64] alpha rows
    volatile unsigned* flg = (volatile unsigned*)(lds + FLAG_OFF);  // [64]
    volatile unsigned* prg = (volatile unsigned*)(lds + PROG_OFF);  // [8]

    const int b    = blockIdx.x;
    const int tid  = threadIdx.x;
    const int w    = tid >> 6;                        // wave 0..7
    const int lane = tid & 63;

    // init sync cells once, before any polling
    if (tid < 64) flg[tid] = 0u;
    if (tid >= 64 && tid < 72) prg[tid - 64] = 0u;
    __syncthreads();

    TAGS_ALL(DECL_TC)                                 // tc_p = T[p][lane]

    // length = sum(mask[b,:])
    const float* mrow = mask + (size_t)b * SLEN;
    float msum = 0.f;
    #pragma unroll
    for (int k = 0; k < SLEN / 64; ++k) msum += mrow[lane + k * 64];
    #pragma unroll
    for (int off = 32; off >= 1; off >>= 1) msum += __shfl_xor(msum, off, 64);
    const int len = (int)msum;                        // in [1024, 2048]

    const float* E = emissions + (size_t)b * SLEN * NTAG;
    int* orow = out + (size_t)b * SLEN;

    if (w == 0) {
        // ---------------- producer: value-only recursion ----------------
        float a = E[lane] + tc1;                      // alpha0
        ring[lane] = a;                               // row 0 -> slot 0
        flg[lane] = 1u;                               // rows <= 0 published

        float e0 = E[NTAG + lane];
        float e1 = E[((2 < len) ? 2 : (len - 1)) * NTAG + lane];
        float e2 = E[((3 < len) ? 3 : (len - 1)) * NTAG + lane];
        float e3 = E[((4 < len) ? 4 : (len - 1)) * NTAG + lane];

        for (int t = 1; t < len; ++t) {
            TAGS_ALL(KEEP_TC)                         // pin T column

            float emit = e0; e0 = e1; e1 = e2; e2 = e3;
            int tn = (t + 4 < len) ? (t + 4) : (len - 1);
            e3 = E[tn * NTAG + lane];

            float bcv = a;
            TAGS_ALL(CAND)                            // 64 readlane+add

            // 64 -> 1 max via v_max3 tree (33 ops; exact: max associative)
            float l0  = FM3(cd0,  cd1,  cd2);
            float l1  = FM3(cd3,  cd4,  cd5);
            float l2  = FM3(cd6,  cd7,  cd8);
            float l3  = FM3(cd9,  cd10, cd11);
            float l4  = FM3(cd12, cd13, cd14);
            float l5  = FM3(cd15, cd16, cd17);
            float l6  = FM3(cd18, cd19, cd20);
            float l7  = FM3(cd21, cd22, cd23);
            float l8  = FM3(cd24, cd25, cd26);
            float l9  = FM3(cd27, cd28, cd29);
            float l10 = FM3(cd30, cd31, cd32);
            float l11 = FM3(cd33, cd34, cd35);
            float l12 = FM3(cd36, cd37, cd38);
            float l13 = FM3(cd39, cd40, cd41);
            float l14 = FM3(cd42, cd43, cd44);
            float l15 = FM3(cd45, cd46, cd47);
            float l16 = FM3(cd48, cd49, cd50);
            float l17 = FM3(cd51, cd52, cd53);
            float l18 = FM3(cd54, cd55, cd56);
            float l19 = FM3(cd57, cd58, cd59);
            float l20 = FM3(cd60, cd61, cd62);
            float m0 = FM3(l0,  l1,  l2);
            float m1 = FM3(l3,  l4,  l5);
            float m2 = FM3(l6,  l7,  l8);
            float m3 = FM3(l9,  l10, l11);
            float m4 = FM3(l12, l13, l14);
            float m5 = FM3(l15, l16, l17);
            float m6 = FM3(l18, l19, l20);
            float n0 = FM3(m0, m1, m2);
            float n1 = FM3(m3, m4, m5);
            float mx = fmaxf(FM3(n0, n1, m6), cd63);

            a = mx + emit;
            ring[(t & (RING_ROWS - 1)) * NTAG + lane] = a;   // publish row t
            flg[lane] = (unsigned)(t + 1);                   // rows <= t done

            // ring-overwrite guard (slack ~48 rows; never trips in practice)
            if ((t & 31) == 0) {
                int g = 0;
                for (;;) {
                    unsigned mn = prg[1];
                    unsigned p2 = prg[2]; if (p2 < mn) mn = p2;
                    unsigned p3 = prg[3]; if (p3 < mn) mn = p3;
                    unsigned p4 = prg[4]; if (p4 < mn) mn = p4;
                    unsigned p5 = prg[5]; if (p5 < mn) mn = p5;
                    unsigned p6 = prg[6]; if (p6 < mn) mn = p6;
                    unsigned p7 = prg[7]; if (p7 < mn) mn = p7;
                    if ((int)mn >= t - 48 || ++g > 1000000) break;
                    __builtin_amdgcn_s_sleep(2);
                }
            }
        }

        // final scores + argmax (value desc, index asc)
        float fin = a + trans[lane * NTAG + EOS_T];
        float v = fin; int idx = lane;
        #pragma unroll
        for (int off = 1; off < 64; off <<= 1) {
            float ov = __shfl_xor(v, off, 64);
            int   oi = __shfl_xor(idx, off, 64);
            if (ov > v || (ov == v && oi < idx)) { v = ov; idx = oi; }
        }
        int cur = idx;                                 // best_last

        for (int i = len + lane; i < SLEN; i += 64) orow[i] = 0;  // PAD
        if (lane == 0) orow[len - 1] = cur;

        // join: wait for all consumers' bt rows
        {
            int g = 0;
            for (;;) {
                unsigned mn = prg[1];
                unsigned p2 = prg[2]; if (p2 < mn) mn = p2;
                unsigned p3 = prg[3]; if (p3 < mn) mn = p3;
                unsigned p4 = prg[4]; if (p4 < mn) mn = p4;
                unsigned p5 = prg[5]; if (p5 < mn) mn = p5;
                unsigned p6 = prg[6]; if (p6 < mn) mn = p6;
                unsigned p7 = prg[7]; if (p7 < mn) mn = p7;
                if (mn == 0x7fffffffu || ++g > 2000000) break;
                __builtin_amdgcn_s_sleep(2);
            }
        }
        asm volatile("" ::: "memory");

        // backtrace (uniform broadcast reads)
        for (int t = len - 2; t >= 0; --t) {
            cur = bt[t * NTAG + cur];
            if (lane == 0) orow[t] = cur;
        }
    } else {
        // -------------- consumers: lagged exact argmax -> bt --------------
        for (int t = w; t < len; t += 7) {
            TAGS_ALL(KEEP_TC)
            int g = 0;
            while (flg[w] < (unsigned)(t + 1)) {       // row t-1 (and t) ready
                __builtin_amdgcn_s_sleep(2);
                if (++g > 2000000) break;
            }
            asm volatile("" ::: "memory");

            float ar = ring[((t - 1) & (RING_ROWS - 1)) * NTAG + lane];
            float bcv = ar;
            TAGS_ALL(CAND)

            // exact first-occurrence argmax (ascending pairs, >= left-bias)
            LEAF(0,  0,  1)  LEAF(1,  2,  3)  LEAF(2,  4,  5)  LEAF(3,  6,  7)
            LEAF(4,  8,  9)  LEAF(5,  10, 11) LEAF(6,  12, 13) LEAF(7,  14, 15)
            LEAF(8,  16, 17) LEAF(9,  18, 19) LEAF(10, 20, 21) LEAF(11, 22, 23)
            LEAF(12, 24, 25) LEAF(13, 26, 27) LEAF(14, 28, 29) LEAF(15, 30, 31)
            LEAF(16, 32, 33) LEAF(17, 34, 35) LEAF(18, 36, 37) LEAF(19, 38, 39)
            LEAF(20, 40, 41) LEAF(21, 42, 43) LEAF(22, 44, 45) LEAF(23, 46, 47)
            LEAF(24, 48, 49) LEAF(25, 50, 51) LEAF(26, 52, 53) LEAF(27, 54, 55)
            LEAF(28, 56, 57) LEAF(29, 58, 59) LEAF(30, 60, 61) LEAF(31, 62, 63)
            MRG(vb0,  ib0,  va0,  ia0,  va1,  ia1)   MRG(vb1,  ib1,  va2,  ia2,  va3,  ia3)
            MRG(vb2,  ib2,  va4,  ia4,  va5,  ia5)   MRG(vb3,  ib3,  va6,  ia6,  va7,  ia7)
            MRG(vb4,  ib4,  va8,  ia8,  va9,  ia9)   MRG(vb5,  ib5,  va10, ia10, va11, ia11)
            MRG(vb6,  ib6,  va12, ia12, va13, ia13)  MRG(vb7,  ib7,  va14, ia14, va15, ia15)
            MRG(vb8,  ib8,  va16, ia16, va17, ia17)  MRG(vb9,  ib9,  va18, ia18, va19, ia19)
            MRG(vb10, ib10, va20, ia20, va21, ia21)  MRG(vb11, ib11, va22, ia22, va23, ia23)
            MRG(vb12, ib12, va24, ia24, va25, ia25)  MRG(vb13, ib13, va26, ia26, va27, ia27)
            MRG(vb14, ib14, va28, ia28, va29, ia29)  MRG(vb15, ib15, va30, ia30, va31, ia31)
            MRG(vc0, ic0, vb0,  ib0,  vb1,  ib1)     MRG(vc1, ic1, vb2,  ib2,  vb3,  ib3)
            MRG(vc2, ic2, vb4,  ib4,  vb5,  ib5)     MRG(vc3, ic3, vb6,  ib6,  vb7,  ib7)
            MRG(vc4, ic4, vb8,  ib8,  vb9,  ib9)     MRG(vc5, ic5, vb10, ib10, vb11, ib11)
            MRG(vc6, ic6, vb12, ib12, vb13, ib13)    MRG(vc7, ic7, vb14, ib14, vb15, ib15)
            MRG(vd0, id0, vc0, ic0, vc1, ic1)        MRG(vd1, id1, vc2, ic2, vc3, ic3)
            MRG(vd2, id2, vc4, ic4, vc5, ic5)        MRG(vd3, id3, vc6, ic6, vc7, ic7)
            MRG(ve0, ie0, vd0, id0, vd1, id1)        MRG(ve1, ie1, vd2, id2, vd3, id3)
            MRG(vf0, if0, ve0, ie0, ve1, ie1)

            bt[(t - 1) * NTAG + lane] = (unsigned char)if0;
            asm volatile("" ::: "memory");             // order bt before prog
            prg[w] = (unsigned)t;
        }
        asm volatile("s_waitcnt lgkmcnt(0)" ::: "memory");  // bt visible
        prg[w] = 0x7fffffffu;
    }
}

extern "C" void kernel_launch(void* const* d_in, const int* in_sizes, int n_in,
                              void* d_out, int out_size, void* d_ws, size_t ws_size,
                              hipStream_t stream) {
    const float* emissions = (const float*)d_in[0];
    const float* mask      = (const float*)d_in[1];
    const float* trans     = (const float*)d_in[2];
    int* out = (int*)d_out;

    (void)hipFuncSetAttribute((const void*)crf_viterbi,
                              hipFuncAttributeMaxDynamicSharedMemorySize,
                              LDS_BYTES);

    crf_viterbi<<<NBATCH, 512, LDS_BYTES, stream>>>(emissions, mask, trans, out);
}

// Round 13
// 952.161 us; speedup vs baseline: 1.2527x; 1.2527x over previous
//
#include <hip/hip_runtime.h>

#define NBATCH 256
#define SLEN   2048
#define NTAG   64
#define BOS_T  1
#define EOS_T  2

#define BT_BYTES 131072
#define LDS_BYTES (BT_BYTES + 2 * NTAG * 4)

typedef float f32x4 __attribute__((ext_vector_type(4)));

#define K8(X) X(0) X(1) X(2) X(3) X(4) X(5) X(6) X(7)
#define DECL_TC(k) float tcv##k = trans[(pbase + k) * NTAG + c];
#define KEEP_TC(k) asm volatile("" : "+v"(tcv##k));
#define FM3(x, y, z) fmaxf(fmaxf((x), (y)), (z))

// index tournament: local prevs ka<kb ascending; >= keeps lower index
#define LEAF(i, ka, kb) \
  float va##i; int ia##i; { bool g_ = (cd##ka >= cd##kb); \
    va##i = g_ ? cd##ka : cd##kb; ia##i = g_ ? (pbase + ka) : (pbase + kb); }
#define MRG(vo, io, vA, iA, vB, iB) \
  float vo; int io; { bool g_ = ((vA) >= (vB)); \
    vo = g_ ? (vA) : (vB); io = g_ ? (iA) : (iB); }

// c-split, mask-free combine: butterfly over lane bits {0,1,4} done with
// DPP quad_perm (xor1, xor2) and v_permlane16_swap (xor16) — all VALU,
// no ds_bpermute/readlane (r11's shfl butterfly and r12's readlane chains
// were the serial-path cost). Value path (pure v_max) publishes alpha
// ASAP; the vcc-serialized index path overlaps the barrier wait.
__global__ __launch_bounds__(512)
__attribute__((amdgpu_waves_per_eu(2, 2)))
void crf_viterbi(const float* __restrict__ emissions,  // [B,S,C]
                 const float* __restrict__ mask,       // [B,S]
                 const float* __restrict__ trans,      // [C,C]
                 int* __restrict__ out)                // [B,S] int32 tags
{
    extern __shared__ unsigned char lds[];
    unsigned char* bt = lds;                   // [S-1][64] backpointers
    float* abuf = (float*)(lds + BT_BYTES);    // [2][64] alpha ping-pong

    const int b    = blockIdx.x;
    const int tid  = threadIdx.x;
    const int w    = tid >> 6;                 // wave 0..7
    const int lane = tid & 63;
    // prev-group on lane bits {0,1,4}; column-local on bits {2,3,5}
    const int p_hi  = (lane & 3) | ((lane & 16) >> 2);
    const int cl    = ((lane >> 2) & 3) | ((lane >> 5) << 2);
    const int c     = (w << 3) + cl;           // this lane's output tag
    const int pbase = p_hi << 3;               // this lane's 8-prev base
    const bool lo16 = (lane & 16) == 0;

    K8(DECL_TC)                                // tcv_k = T[pbase+k][c]

    // length = sum(mask[b,:])
    const float* mrow = mask + (size_t)b * SLEN;
    float msum = 0.f;
    #pragma unroll
    for (int k = 0; k < SLEN / 64; ++k) msum += mrow[lane + k * 64];
    #pragma unroll
    for (int off = 32; off >= 1; off >>= 1) msum += __shfl_xor(msum, off, 64);
    const int len = (int)msum;                 // in [1024, 2048]

    const float* E = emissions + (size_t)b * SLEN * NTAG;

    // alpha0
    if (p_hi == 0) abuf[c] = E[c] + trans[BOS_T * NTAG + c];
    asm volatile("s_waitcnt lgkmcnt(0)\n\ts_barrier" ::: "memory");

    // depth-4 emissions prefetch (raw barrier never drains vmcnt)
    float e0 = E[NTAG + c];
    float e1 = E[((2 < len) ? 2 : (len - 1)) * NTAG + c];
    float e2 = E[((3 < len) ? 3 : (len - 1)) * NTAG + c];
    float e3 = E[((4 < len) ? 4 : (len - 1)) * NTAG + c];

    for (int t = 1; t < len; ++t) {
        K8(KEEP_TC)

        float emit = e0; e0 = e1; e1 = e2; e2 = e3;
        int tn = (t + 4 < len) ? (t + 4) : (len - 1);
        e3 = E[tn * NTAG + c];

        // read own 8 prev alphas (broadcast within p_hi group; 2-way alias)
        const f32x4* ab = (const f32x4*)(abuf + ((t ^ 1) & 1) * NTAG);
        f32x4 al0 = ab[(p_hi << 1)];
        f32x4 al1 = ab[(p_hi << 1) + 1];
        float cd0 = al0[0] + tcv0, cd1 = al0[1] + tcv1;
        float cd2 = al0[2] + tcv2, cd3 = al0[3] + tcv3;
        float cd4 = al1[0] + tcv4, cd5 = al1[1] + tcv5;
        float cd6 = al1[2] + tcv6, cd7 = al1[3] + tcv7;

        // ---- value path: pure max tree (exact, mask-free) ----
        float u0 = FM3(cd0, cd1, cd2);
        float u1 = FM3(cd3, cd4, cd5);
        float u2 = fmaxf(cd6, cd7);
        float v  = FM3(u0, u1, u2);

        // ---- index path: exact first-occurrence within the 8 ----
        LEAF(0, 0, 1) LEAF(1, 2, 3) LEAF(2, 4, 5) LEAF(3, 6, 7)
        MRG(vb0, ib0, va0, ia0, va1, ia1)
        MRG(vb1, ib1, va2, ia2, va3, ia3)
        MRG(vf0, if0, vb0, ib0, vb1, ib1)
        int ii = if0;                           // vf0 == v exactly

        // ---- butterfly over p_hi bits: xor1, xor2 (DPP), xor16 (permlane) ----
        // stage xor1: quad_perm [1,0,3,2] = 0xB1
        {
            float pv = __int_as_float(__builtin_amdgcn_update_dpp(
                0, __float_as_int(v), 0xB1, 0xF, 0xF, true));
            int pi = __builtin_amdgcn_update_dpp(0, ii, 0xB1, 0xF, 0xF, true);
            bool take = (pv > v) || (pv == v && pi < ii);
            ii = take ? pi : ii;
            v  = fmaxf(v, pv);
        }
        // stage xor2: quad_perm [2,3,0,1] = 0x4E
        {
            float pv = __int_as_float(__builtin_amdgcn_update_dpp(
                0, __float_as_int(v), 0x4E, 0xF, 0xF, true));
            int pi = __builtin_amdgcn_update_dpp(0, ii, 0x4E, 0xF, 0xF, true);
            bool take = (pv > v) || (pv == v && pi < ii);
            ii = take ? pi : ii;
            v  = fmaxf(v, pv);
        }
        // stage xor16: v_permlane16_swap (partner in y for lane&16==0, else x)
        {
            float x = v, y = v;
            asm volatile("v_permlane16_swap_b32 %0, %1" : "+v"(x), "+v"(y));
            int xi = ii, yi = ii;
            asm volatile("v_permlane16_swap_b32 %0, %1" : "+v"(xi), "+v"(yi));
            float pv = lo16 ? y : x;
            int   pi = lo16 ? yi : xi;
            bool take = (pv > v) || (pv == v && pi < ii);
            ii = take ? pi : ii;
            v  = fmaxf(x, y);                   // = max(v, pv)
        }

        float anew = v + emit;
        if (p_hi == 0) {
            abuf[(t & 1) * NTAG + c] = anew;              // publish alpha[t]
            bt[(t - 1) * NTAG + c] = (unsigned char)ii;   // backpointer
        }
        asm volatile("s_waitcnt lgkmcnt(0)\n\ts_barrier" ::: "memory");
    }

    const float* afin = abuf + ((len - 1) & 1) * NTAG;

    int* orow = out + (size_t)b * SLEN;
    for (int i = len + tid; i < SLEN; i += 512) orow[i] = 0;   // PAD tail

    if (w != 0) return;                         // no barriers remain

    // wave 0: final argmax (value desc, index asc) over alpha + T[:,EOS]
    float fin = afin[lane] + trans[lane * NTAG + EOS_T];
    float fv = fin; int idx = lane;
    #pragma unroll
    for (int off = 1; off < 64; off <<= 1) {
        float ov = __shfl_xor(fv, off, 64);
        int   oi = __shfl_xor(idx, off, 64);
        if (ov > fv || (ov == fv && oi < idx)) { fv = ov; idx = oi; }
    }
    int cur = idx;                              // best_last (uniform)

    if (lane == 0) orow[len - 1] = cur;

    // backtrace through LDS backpointers (uniform broadcast reads)
    asm volatile("s_waitcnt lgkmcnt(0)" ::: "memory");
    for (int t = len - 2; t >= 0; --t) {
        cur = bt[t * NTAG + cur];
        if (lane == 0) orow[t] = cur;
    }
}

extern "C" void kernel_launch(void* const* d_in, const int* in_sizes, int n_in,
                              void* d_out, int out_size, void* d_ws, size_t ws_size,
                              hipStream_t stream) {
    const float* emissions = (const float*)d_in[0];
    const float* mask      = (const float*)d_in[1];
    const float* trans     = (const float*)d_in[2];
    int* out = (int*)d_out;

    (void)hipFuncSetAttribute((const void*)crf_viterbi,
                              hipFuncAttributeMaxDynamicSharedMemorySize,
                              LDS_BYTES);

    crf_viterbi<<<NBATCH, 512, LDS_BYTES, stream>>>(emissions, mask, trans, out);
}

// Round 14
// 905.557 us; speedup vs baseline: 1.3171x; 1.0515x over previous
//
#include <hip/hip_runtime.h>

#define NBATCH 256
#define SLEN   2048
#define NTAG   64
#define BOS_T  1
#define EOS_T  2

#define BT_BYTES  131072
#define RING_ROWS 16
#define RING_BYTES (RING_ROWS * NTAG * 4)      // 4096
#define FLAG_OFF  (BT_BYTES + RING_BYTES)      // 135168
#define PROG_OFF  (FLAG_OFF + 16)              // 135184
#define LDS_BYTES (PROG_OFF + 16)              // 135200 < 160K

typedef float f32x4 __attribute__((ext_vector_type(4)));

#define TAGS_ALL(X) \
  X(0)  X(1)  X(2)  X(3)  X(4)  X(5)  X(6)  X(7)  \
  X(8)  X(9)  X(10) X(11) X(12) X(13) X(14) X(15) \
  X(16) X(17) X(18) X(19) X(20) X(21) X(22) X(23) \
  X(24) X(25) X(26) X(27) X(28) X(29) X(30) X(31) \
  X(32) X(33) X(34) X(35) X(36) X(37) X(38) X(39) \
  X(40) X(41) X(42) X(43) X(44) X(45) X(46) X(47) \
  X(48) X(49) X(50) X(51) X(52) X(53) X(54) X(55) \
  X(56) X(57) X(58) X(59) X(60) X(61) X(62) X(63)

#define DECL_TC(p) float tc##p = trans[(p) * NTAG + lane];
#define KEEP_TC(p) asm volatile("" : "+v"(tc##p));

#define Q_ALL(X) X(0) X(1) X(2) X(3) X(4) X(5) X(6) X(7) \
                 X(8) X(9) X(10) X(11) X(12) X(13) X(14) X(15)
#define DECL_RR(q) f32x4 rr##q = rp[q];

// cd_p = alpha_prev[p] (broadcast LDS row) + T[p][c]
#define MKCD(q, a0, a1, a2, a3) \
  float cd##a0 = rr##q[0] + tc##a0; float cd##a1 = rr##q[1] + tc##a1; \
  float cd##a2 = rr##q[2] + tc##a2; float cd##a3 = rr##q[3] + tc##a3;
#define ALL_CD() \
  MKCD(0,0,1,2,3)      MKCD(1,4,5,6,7)      MKCD(2,8,9,10,11)    MKCD(3,12,13,14,15) \
  MKCD(4,16,17,18,19)  MKCD(5,20,21,22,23)  MKCD(6,24,25,26,27)  MKCD(7,28,29,30,31) \
  MKCD(8,32,33,34,35)  MKCD(9,36,37,38,39)  MKCD(10,40,41,42,43) MKCD(11,44,45,46,47) \
  MKCD(12,48,49,50,51) MKCD(13,52,53,54,55) MKCD(14,56,57,58,59) MKCD(15,60,61,62,63)

#define FM3(x, y, z) fmaxf(fmaxf((x), (y)), (z))

// exact first-occurrence argmax tournament (ascending pairs, >= left-bias)
#define LEAF(i, pa, pb) \
  float va##i; int ia##i; { bool g_ = (cd##pa >= cd##pb); \
    va##i = g_ ? cd##pa : cd##pb; ia##i = g_ ? (pa) : (pb); }
#define MRG(vo, io, vA, iA, vB, iB) \
  float vo; int io; { bool g_ = ((vA) >= (vB)); \
    vo = g_ ? (vA) : (vB); io = g_ ? (iA) : (iB); }

// Producer/consumer v2: r12's architecture with the readlane chains excised.
// Producer (wave 0): value recursion via LDS-broadcast row (1 ds_write + 16
// uniform ds_read_b128; in-wave pipe order => NO sync on the serial cycle).
// Consumers (waves 1-3): lagged exact argmax -> bt, flag-gated.
// waves_per_eu(1,1): 135KB LDS -> 1 wg/CU; full VGPR budget (tc resident).
__global__ __launch_bounds__(256)
__attribute__((amdgpu_waves_per_eu(1, 1)))
void crf_viterbi(const float* __restrict__ emissions,  // [B,S,C]
                 const float* __restrict__ mask,       // [B,S]
                 const float* __restrict__ trans,      // [C,C]
                 int* __restrict__ out)                // [B,S] int32 tags
{
    extern __shared__ unsigned char lds[];
    unsigned char* bt = lds;                             // [S-1][64]
    float* ring = (float*)(lds + BT_BYTES);              // [16][64] alpha rows
    volatile unsigned* flg = (volatile unsigned*)(lds + FLAG_OFF);  // [1]
    volatile unsigned* prg = (volatile unsigned*)(lds + PROG_OFF);  // [4]

    const int b    = blockIdx.x;
    const int tid  = threadIdx.x;
    const int w    = tid >> 6;                           // wave 0..3
    const int lane = tid & 63;

    if (tid == 0) flg[0] = 0u;
    if (tid >= 1 && tid <= 3) prg[tid] = 0u;
    __syncthreads();                                     // once, pre-loop

    TAGS_ALL(DECL_TC)                                    // tc_p = T[p][lane]

    // length = sum(mask[b,:]) (each wave independently; identical result)
    const float* mrow = mask + (size_t)b * SLEN;
    float msum = 0.f;
    #pragma unroll
    for (int k = 0; k < SLEN / 64; ++k) msum += mrow[lane + k * 64];
    #pragma unroll
    for (int off = 32; off >= 1; off >>= 1) msum += __shfl_xor(msum, off, 64);
    const int len = (int)msum;                           // in [1024, 2048]

    const float* E = emissions + (size_t)b * SLEN * NTAG;
    int* orow = out + (size_t)b * SLEN;

    if (w == 0) {
        // ------------- producer: value-only, no sync on the cycle -------------
        float a = E[lane] + tc1;                         // alpha0
        ring[lane] = a;                                  // row 0 -> slot 0
        asm volatile("" ::: "memory");                   // order row before flag
        if (lane == 0) flg[0] = 1u;                      // rows <= 0 published

        float e0 = E[NTAG + lane];
        float e1 = E[((2 < len) ? 2 : (len - 1)) * NTAG + lane];
        float e2 = E[((3 < len) ? 3 : (len - 1)) * NTAG + lane];
        float e3 = E[((4 < len) ? 4 : (len - 1)) * NTAG + lane];

        for (int t = 1; t < len; ++t) {
            TAGS_ALL(KEEP_TC)                            // pin T column

            float emit = e0; e0 = e1; e1 = e2; e2 = e3;
            int tn = (t + 4 < len) ? (t + 4) : (len - 1);
            e3 = E[tn * NTAG + lane];

            // broadcast read of alpha row t-1 (own write of last iter;
            // in-wave LDS pipe order => no explicit fence needed)
            const f32x4* rp = (const f32x4*)(ring + ((t - 1) & (RING_ROWS - 1)) * NTAG);
            Q_ALL(DECL_RR)
            ALL_CD()

            // 64 -> 1 max via max3 tree (exact: max is associative)
            float l0  = FM3(cd0,  cd1,  cd2);
            float l1  = FM3(cd3,  cd4,  cd5);
            float l2  = FM3(cd6,  cd7,  cd8);
            float l3  = FM3(cd9,  cd10, cd11);
            float l4  = FM3(cd12, cd13, cd14);
            float l5  = FM3(cd15, cd16, cd17);
            float l6  = FM3(cd18, cd19, cd20);
            float l7  = FM3(cd21, cd22, cd23);
            float l8  = FM3(cd24, cd25, cd26);
            float l9  = FM3(cd27, cd28, cd29);
            float l10 = FM3(cd30, cd31, cd32);
            float l11 = FM3(cd33, cd34, cd35);
            float l12 = FM3(cd36, cd37, cd38);
            float l13 = FM3(cd39, cd40, cd41);
            float l14 = FM3(cd42, cd43, cd44);
            float l15 = FM3(cd45, cd46, cd47);
            float l16 = FM3(cd48, cd49, cd50);
            float l17 = FM3(cd51, cd52, cd53);
            float l18 = FM3(cd54, cd55, cd56);
            float l19 = FM3(cd57, cd58, cd59);
            float l20 = FM3(cd60, cd61, cd62);
            float m0 = FM3(l0,  l1,  l2);
            float m1 = FM3(l3,  l4,  l5);
            float m2 = FM3(l6,  l7,  l8);
            float m3 = FM3(l9,  l10, l11);
            float m4 = FM3(l12, l13, l14);
            float m5 = FM3(l15, l16, l17);
            float m6 = FM3(l18, l19, l20);
            float n0 = FM3(m0, m1, m2);
            float n1 = FM3(m3, m4, m5);
            float mx = fmaxf(FM3(n0, n1, m6), cd63);

            a = mx + emit;
            ring[(t & (RING_ROWS - 1)) * NTAG + lane] = a;   // publish row t
            asm volatile("" ::: "memory");                   // row before flag
            if (lane == 0) flg[0] = (unsigned)(t + 1);       // rows <= t done

            // ring-overwrite guard: need min(prog) >= t-8 every 8 steps
            if ((t & 7) == 0) {
                int g = 0;
                for (;;) {
                    unsigned m1_ = prg[1], m2_ = prg[2], m3_ = prg[3];
                    unsigned mn = m1_ < m2_ ? m1_ : m2_;
                    mn = mn < m3_ ? mn : m3_;
                    if ((int)mn >= t - 8 || ++g > 2000000) break;
                    __builtin_amdgcn_s_sleep(2);
                }
            }
        }

        // final scores + argmax (value desc, index asc)
        float fin = a + trans[lane * NTAG + EOS_T];
        float v = fin; int idx = lane;
        #pragma unroll
        for (int off = 1; off < 64; off <<= 1) {
            float ov = __shfl_xor(v, off, 64);
            int   oi = __shfl_xor(idx, off, 64);
            if (ov > v || (ov == v && oi < idx)) { v = ov; idx = oi; }
        }
        int cur = idx;                                   // best_last

        for (int i = len + lane; i < SLEN; i += 64) orow[i] = 0;  // PAD
        if (lane == 0) orow[len - 1] = cur;

        // join: all consumers done (bounded poll)
        {
            int g = 0;
            for (;;) {
                unsigned m1_ = prg[1], m2_ = prg[2], m3_ = prg[3];
                unsigned mn = m1_ < m2_ ? m1_ : m2_;
                mn = mn < m3_ ? mn : m3_;
                if (mn == 0x7fffffffu || ++g > 2000000) break;
                __builtin_amdgcn_s_sleep(2);
            }
        }
        asm volatile("" ::: "memory");

        // backtrace through LDS backpointers (uniform broadcast reads)
        for (int t = len - 2; t >= 0; --t) {
            cur = bt[t * NTAG + cur];
            if (lane == 0) orow[t] = cur;
        }
    } else {
        // ------------- consumers: lagged exact argmax -> bt -------------
        for (int t = w; t < len; t += 3) {
            TAGS_ALL(KEEP_TC)
            int g = 0;
            while (flg[0] < (unsigned)t) {               // need rows <= t-1
                __builtin_amdgcn_s_sleep(2);
                if (++g > 2000000) break;
            }
            asm volatile("" ::: "memory");

            const f32x4* rp = (const f32x4*)(ring + ((t - 1) & (RING_ROWS - 1)) * NTAG);
            Q_ALL(DECL_RR)
            ALL_CD()

            LEAF(0,  0,  1)  LEAF(1,  2,  3)  LEAF(2,  4,  5)  LEAF(3,  6,  7)
            LEAF(4,  8,  9)  LEAF(5,  10, 11) LEAF(6,  12, 13) LEAF(7,  14, 15)
            LEAF(8,  16, 17) LEAF(9,  18, 19) LEAF(10, 20, 21) LEAF(11, 22, 23)
            LEAF(12, 24, 25) LEAF(13, 26, 27) LEAF(14, 28, 29) LEAF(15, 30, 31)
            LEAF(16, 32, 33) LEAF(17, 34, 35) LEAF(18, 36, 37) LEAF(19, 38, 39)
            LEAF(20, 40, 41) LEAF(21, 42, 43) LEAF(22, 44, 45) LEAF(23, 46, 47)
            LEAF(24, 48, 49) LEAF(25, 50, 51) LEAF(26, 52, 53) LEAF(27, 54, 55)
            LEAF(28, 56, 57) LEAF(29, 58, 59) LEAF(30, 60, 61) LEAF(31, 62, 63)
            MRG(vb0,  ib0,  va0,  ia0,  va1,  ia1)   MRG(vb1,  ib1,  va2,  ia2,  va3,  ia3)
            MRG(vb2,  ib2,  va4,  ia4,  va5,  ia5)   MRG(vb3,  ib3,  va6,  ia6,  va7,  ia7)
            MRG(vb4,  ib4,  va8,  ia8,  va9,  ia9)   MRG(vb5,  ib5,  va10, ia10, va11, ia11)
            MRG(vb6,  ib6,  va12, ia12, va13, ia13)  MRG(vb7,  ib7,  va14, ia14, va15, ia15)
            MRG(vb8,  ib8,  va16, ia16, va17, ia17)  MRG(vb9,  ib9,  va18, ia18, va19, ia19)
            MRG(vb10, ib10, va20, ia20, va21, ia21)  MRG(vb11, ib11, va22, ia22, va23, ia23)
            MRG(vb12, ib12, va24, ia24, va25, ia25)  MRG(vb13, ib13, va26, ia26, va27, ia27)
            MRG(vb14, ib14, va28, ia28, va29, ia29)  MRG(vb15, ib15, va30, ia30, va31, ia31)
            MRG(vc0, ic0, vb0,  ib0,  vb1,  ib1)     MRG(vc1, ic1, vb2,  ib2,  vb3,  ib3)
            MRG(vc2, ic2, vb4,  ib4,  vb5,  ib5)     MRG(vc3, ic3, vb6,  ib6,  vb7,  ib7)
            MRG(vc4, ic4, vb8,  ib8,  vb9,  ib9)     MRG(vc5, ic5, vb10, ib10, vb11, ib11)
            MRG(vc6, ic6, vb12, ib12, vb13, ib13)    MRG(vc7, ic7, vb14, ib14, vb15, ib15)
            MRG(vd0, id0, vc0, ic0, vc1, ic1)        MRG(vd1, id1, vc2, ic2, vc3, ic3)
            MRG(vd2, id2, vc4, ic4, vc5, ic5)        MRG(vd3, id3, vc6, ic6, vc7, ic7)
            MRG(ve0, ie0, vd0, id0, vd1, id1)        MRG(ve1, ie1, vd2, id2, vd3, id3)
            MRG(vf0, if0, ve0, ie0, ve1, ie1)

            bt[(t - 1) * NTAG + lane] = (unsigned char)if0;
            asm volatile("" ::: "memory");               // bt before prog
            prg[w] = (unsigned)t;
        }
        asm volatile("s_waitcnt lgkmcnt(0)" ::: "memory");   // bt visible
        prg[w] = 0x7fffffffu;
    }
}

extern "C" void kernel_launch(void* const* d_in, const int* in_sizes, int n_in,
                              void* d_out, int out_size, void* d_ws, size_t ws_size,
                              hipStream_t stream) {
    const float* emissions = (const float*)d_in[0];
    const float* mask      = (const float*)d_in[1];
    const float* trans     = (const float*)d_in[2];
    int* out = (int*)d_out;

    (void)hipFuncSetAttribute((const void*)crf_viterbi,
                              hipFuncAttributeMaxDynamicSharedMemorySize,
                              LDS_BYTES);

    crf_viterbi<<<NBATCH, 256, LDS_BYTES, stream>>>(emissions, mask, trans, out);
}

// Round 15
// 791.358 us; speedup vs baseline: 1.5072x; 1.1443x over previous
//
#include <hip/hip_runtime.h>

#define NBATCH 256
#define SLEN   2048
#define NTAG   64
#define BOS_T  1
#define EOS_T  2

#define BT_BYTES  131072
#define RING_ROWS 32
#define RING_BYTES (RING_ROWS * NTAG * 4)          // 8192
#define FLAG_OFF  (BT_BYTES + RING_BYTES)          // 139264
#define PRG_OFF   (FLAG_OFF + 16)                  // 139280
#define MAPS_OFF  (PRG_OFF + 16)                   // 139296 (64x64 u8)
#define BTAG_OFF  (MAPS_OFF + 4096)                // 143392 (65 x i32)
#define LDS_BYTES (BTAG_OFF + 272)                 // 143664 < 160K

typedef float f32x2 __attribute__((ext_vector_type(2)));
typedef float f32x4 __attribute__((ext_vector_type(4)));

#define Q16(X) X(0) X(1) X(2) X(3) X(4) X(5) X(6) X(7) \
               X(8) X(9) X(10) X(11) X(12) X(13) X(14) X(15)

// T column as 32 f32x2 pairs: tpA_q = {T[4q][c],T[4q+1][c]}, tpB_q = {T[4q+2][c],T[4q+3][c]}
#define DECL_TP(q) \
  f32x2 tpA##q = { trans[(4*(q)+0)*NTAG + lane], trans[(4*(q)+1)*NTAG + lane] }; \
  f32x2 tpB##q = { trans[(4*(q)+2)*NTAG + lane], trans[(4*(q)+3)*NTAG + lane] };
#define KEEP_TP(q) asm volatile("" : "+v"(tpA##q), "+v"(tpB##q));

#define DECL_RR(q) f32x4 rr##q = rp[q];

// producer: packed adds (v_pk_add_f32) + quad max (max3+max), exact
#define PKC(q) \
  f32x2 cpA##q = (f32x2){rr##q[0], rr##q[1]} + tpA##q; \
  f32x2 cpB##q = (f32x2){rr##q[2], rr##q[3]} + tpB##q; \
  float qm##q = fmaxf(fmaxf(fmaxf(cpA##q[0], cpA##q[1]), cpB##q[0]), cpB##q[1]);

#define FM3(x, y, z) fmaxf(fmaxf((x), (y)), (z))

// consumer: scalar candidates cd0..cd63 (same values, exact)
#define MKCD(q, a0, a1, a2, a3) \
  float cd##a0 = rr##q[0] + tpA##q[0]; float cd##a1 = rr##q[1] + tpA##q[1]; \
  float cd##a2 = rr##q[2] + tpB##q[0]; float cd##a3 = rr##q[3] + tpB##q[1];
#define ALL_CD() \
  MKCD(0,0,1,2,3)      MKCD(1,4,5,6,7)      MKCD(2,8,9,10,11)    MKCD(3,12,13,14,15) \
  MKCD(4,16,17,18,19)  MKCD(5,20,21,22,23)  MKCD(6,24,25,26,27)  MKCD(7,28,29,30,31) \
  MKCD(8,32,33,34,35)  MKCD(9,36,37,38,39)  MKCD(10,40,41,42,43) MKCD(11,44,45,46,47) \
  MKCD(12,48,49,50,51) MKCD(13,52,53,54,55) MKCD(14,56,57,58,59) MKCD(15,60,61,62,63)

// exact first-occurrence argmax tournament (ascending pairs, >= left-bias)
#define LEAF(i, pa, pb) \
  float va##i; int ia##i; { bool g_ = (cd##pa >= cd##pb); \
    va##i = g_ ? cd##pa : cd##pb; ia##i = g_ ? (pa) : (pb); }
#define MRG(vo, io, vA, iA, vB, iB) \
  float vo; int io; { bool g_ = ((vA) >= (vB)); \
    vo = g_ ? (vA) : (vB); io = g_ ? (iA) : (iB); }

__global__ __launch_bounds__(256)
__attribute__((amdgpu_waves_per_eu(1, 1)))
void crf_viterbi(const float* __restrict__ emissions,  // [B,S,C]
                 const float* __restrict__ mask,       // [B,S]
                 const float* __restrict__ trans,      // [C,C]
                 int* __restrict__ out)                // [B,S] int32 tags
{
    extern __shared__ unsigned char lds[];
    unsigned char* bt   = lds;                               // [S-1][64]
    float*         ring = (float*)(lds + BT_BYTES);          // [32][64]
    volatile unsigned* flg = (volatile unsigned*)(lds + FLAG_OFF);
    volatile unsigned* prg = (volatile unsigned*)(lds + PRG_OFF);
    unsigned char* maps = lds + MAPS_OFF;                    // [64][64]
    int*           btag = (int*)(lds + BTAG_OFF);            // [65]

    const int b    = blockIdx.x;
    const int tid  = threadIdx.x;
    const int w    = tid >> 6;                               // wave 0..3
    const int lane = tid & 63;

    if (tid == 0) flg[0] = 0u;
    if (tid >= 1 && tid <= 3) prg[tid] = 0u;
    __syncthreads();

    Q16(DECL_TP)                                             // T in VGPR pairs

    // length = sum(mask[b,:])
    const float* mrow = mask + (size_t)b * SLEN;
    float msum = 0.f;
    #pragma unroll
    for (int k = 0; k < SLEN / 64; ++k) msum += mrow[lane + k * 64];
    #pragma unroll
    for (int off = 32; off >= 1; off >>= 1) msum += __shfl_xor(msum, off, 64);
    const int len = (int)msum;                               // in [1024, 2048]
    const int K   = (len - 1 + 31) >> 5;                     // backtrace chunks

    const float* E = emissions + (size_t)b * SLEN * NTAG;
    int* orow = out + (size_t)b * SLEN;

    if (w == 0) {
        // ------------- producer: value-only, no sync on the cycle -------------
        float a = E[lane] + tpA0[1];                         // alpha0 (+T[BOS])
        ring[lane] = a;
        asm volatile("" ::: "memory");
        if (lane == 0) flg[0] = 1u;

        float e0 = E[NTAG + lane];
        float e1 = E[((2 < len) ? 2 : (len - 1)) * NTAG + lane];
        float e2 = E[((3 < len) ? 3 : (len - 1)) * NTAG + lane];
        float e3 = E[((4 < len) ? 4 : (len - 1)) * NTAG + lane];

        for (int t = 1; t < len; ++t) {
            float emit = e0; e0 = e1; e1 = e2; e2 = e3;
            int tn = (t + 4 < len) ? (t + 4) : (len - 1);
            e3 = E[tn * NTAG + lane];

            const f32x4* rp = (const f32x4*)(ring + ((t - 1) & (RING_ROWS - 1)) * NTAG);
            Q16(DECL_RR)
            Q16(PKC)                                         // 32 pk_add + 32 max

            float s0 = FM3(qm0,  qm1,  qm2);
            float s1 = FM3(qm3,  qm4,  qm5);
            float s2 = FM3(qm6,  qm7,  qm8);
            float s3 = FM3(qm9,  qm10, qm11);
            float s4 = FM3(qm12, qm13, qm14);
            float u0 = FM3(s0, s1, s2);
            float u1 = fmaxf(s3, s4);
            float mx = FM3(u0, u1, qm15);

            a = mx + emit;
            ring[(t & (RING_ROWS - 1)) * NTAG + lane] = a;   // publish row t
            asm volatile("" ::: "memory");
            if (lane == 0) flg[0] = (unsigned)(t + 1);

            // ring-overwrite guard (32-row ring, threshold t-16: ample slack)
            if ((t & 7) == 0) {
                int g = 0;
                for (;;) {
                    unsigned m1_ = prg[1], m2_ = prg[2], m3_ = prg[3];
                    unsigned mn = m1_ < m2_ ? m1_ : m2_;
                    mn = mn < m3_ ? mn : m3_;
                    if ((int)mn >= t - 16 || ++g > 2000000) break;
                    __builtin_amdgcn_s_sleep(8);
                }
            }
            Q16(KEEP_TP)                                     // loop-carried pin
        }

        // final scores + argmax (value desc, index asc)
        float fin = a + trans[lane * NTAG + EOS_T];
        float v = fin; int idx = lane;
        #pragma unroll
        for (int off = 1; off < 64; off <<= 1) {
            float ov = __shfl_xor(v, off, 64);
            int   oi = __shfl_xor(idx, off, 64);
            if (ov > v || (ov == v && oi < idx)) { v = ov; idx = oi; }
        }
        int best_last = idx;

        for (int i = len + lane; i < SLEN; i += 64) orow[i] = 0;   // PAD
        if (lane == 0) {
            orow[len - 1] = best_last;
            btag[K] = best_last;                             // backtrace seed
        }
    } else {
        // ------------- consumers: lagged exact argmax -> bt -------------
        for (int t = w; t < len; t += 3) {
            int g = 0;
            while (flg[0] < (unsigned)t) {                   // rows <= t-1 ready
                __builtin_amdgcn_s_sleep(16);                // ~1024cyc backoff
                if (++g > 200000) break;
            }
            asm volatile("" ::: "memory");

            const f32x4* rp = (const f32x4*)(ring + ((t - 1) & (RING_ROWS - 1)) * NTAG);
            Q16(DECL_RR)
            ALL_CD()

            LEAF(0,  0,  1)  LEAF(1,  2,  3)  LEAF(2,  4,  5)  LEAF(3,  6,  7)
            LEAF(4,  8,  9)  LEAF(5,  10, 11) LEAF(6,  12, 13) LEAF(7,  14, 15)
            LEAF(8,  16, 17) LEAF(9,  18, 19) LEAF(10, 20, 21) LEAF(11, 22, 23)
            LEAF(12, 24, 25) LEAF(13, 26, 27) LEAF(14, 28, 29) LEAF(15, 30, 31)
            LEAF(16, 32, 33) LEAF(17, 34, 35) LEAF(18, 36, 37) LEAF(19, 38, 39)
            LEAF(20, 40, 41) LEAF(21, 42, 43) LEAF(22, 44, 45) LEAF(23, 46, 47)
            LEAF(24, 48, 49) LEAF(25, 50, 51) LEAF(26, 52, 53) LEAF(27, 54, 55)
            LEAF(28, 56, 57) LEAF(29, 58, 59) LEAF(30, 60, 61) LEAF(31, 62, 63)
            MRG(vb0,  ib0,  va0,  ia0,  va1,  ia1)   MRG(vb1,  ib1,  va2,  ia2,  va3,  ia3)
            MRG(vb2,  ib2,  va4,  ia4,  va5,  ia5)   MRG(vb3,  ib3,  va6,  ia6,  va7,  ia7)
            MRG(vb4,  ib4,  va8,  ia8,  va9,  ia9)   MRG(vb5,  ib5,  va10, ia10, va11, ia11)
            MRG(vb6,  ib6,  va12, ia12, va13, ia13)  MRG(vb7,  ib7,  va14, ia14, va15, ia15)
            MRG(vb8,  ib8,  va16, ia16, va17, ia17)  MRG(vb9,  ib9,  va18, ia18, va19, ia19)
            MRG(vb10, ib10, va20, ia20, va21, ia21)  MRG(vb11, ib11, va22, ia22, va23, ia23)
            MRG(vb12, ib12, va24, ia24, va25, ia25)  MRG(vb13, ib13, va26, ia26, va27, ia27)
            MRG(vb14, ib14, va28, ia28, va29, ia29)  MRG(vb15, ib15, va30, ia30, va31, ia31)
            MRG(vc0, ic0, vb0,  ib0,  vb1,  ib1)     MRG(vc1, ic1, vb2,  ib2,  vb3,  ib3)
            MRG(vc2, ic2, vb4,  ib4,  vb5,  ib5)     MRG(vc3, ic3, vb6,  ib6,  vb7,  ib7)
            MRG(vc4, ic4, vb8,  ib8,  vb9,  ib9)     MRG(vc5, ic5, vb10, ib10, vb11, ib11)
            MRG(vc6, ic6, vb12, ib12, vb13, ib13)    MRG(vc7, ic7, vb14, ib14, vb15, ib15)
            MRG(vd0, id0, vc0, ic0, vc1, ic1)        MRG(vd1, id1, vc2, ic2, vc3, ic3)
            MRG(vd2, id2, vc4, ic4, vc5, ic5)        MRG(vd3, id3, vc6, ic6, vc7, ic7)
            MRG(ve0, ie0, vd0, id0, vd1, id1)        MRG(ve1, ie1, vd2, id2, vd3, id3)
            MRG(vf0, if0, ve0, ie0, ve1, ie1)

            bt[(t - 1) * NTAG + lane] = (unsigned char)if0;
            asm volatile("" ::: "memory");
            prg[w] = (unsigned)t;
            Q16(KEEP_TP)
        }
    }

    // ==================== join: bt + seed visible to all ====================
    __syncthreads();

    // ---- phase 1: per-chunk tag maps; wave w owns chunks w, w+4, ... ----
    // lane = entry tag; 16 interleaved chunks/wave hide LDS latency
    {
        #define C16(X) X(0) X(1) X(2) X(3) X(4) X(5) X(6) X(7) \
                       X(8) X(9) X(10) X(11) X(12) X(13) X(14) X(15)
        #define DECLCUR(i) \
          const int k##i = w + 4*(i); const int base##i = k##i << 5; \
          int top##i = base##i + 32; if (top##i > len - 1) top##i = len - 1; \
          const int steps##i = (k##i < K) ? (top##i - base##i) : 0; \
          int cur##i = lane;
        C16(DECLCUR)
        for (int j = 0; j < 32; ++j) {
            #define STEPC(i) if (j < steps##i) \
                cur##i = bt[(top##i - 1 - j) * NTAG + cur##i];
            C16(STEPC)
        }
        #define STOREM(i) if (k##i < K) maps[(k##i << 6) + lane] = (unsigned char)cur##i;
        C16(STOREM)
    }
    __syncthreads();

    // ---- phase 2: compose boundary tags (wave 0; uniform broadcast reads) ----
    if (w == 0) {
        int cur = btag[K];
        for (int k = K - 1; k >= 0; --k) {
            cur = maps[(k << 6) + cur];
            if (lane == 0) btag[k] = cur;
        }
    }
    __syncthreads();

    // ---- phase 3: guided re-chase, write outputs (uniform; lane 0 stores) ----
    {
        #define DECLR(i) \
          const int rk##i = w + 4*(i); const int rb##i = rk##i << 5; \
          int rt##i = rb##i + 32; if (rt##i > len - 1) rt##i = len - 1; \
          const int rs##i = (rk##i < K) ? (rt##i - rb##i) : 0; \
          int rc##i = (rk##i < K) ? btag[rk##i + 1] : 0;
        C16(DECLR)
        for (int j = 0; j < 32; ++j) {
            #define STEPR(i) if (j < rs##i) { \
                const int t_ = rt##i - 1 - j; \
                rc##i = bt[t_ * NTAG + rc##i]; \
                if (lane == 0) orow[t_] = rc##i; }
            C16(STEPR)
        }
    }
}

extern "C" void kernel_launch(void* const* d_in, const int* in_sizes, int n_in,
                              void* d_out, int out_size, void* d_ws, size_t ws_size,
                              hipStream_t stream) {
    const float* emissions = (const float*)d_in[0];
    const float* mask      = (const float*)d_in[1];
    const float* trans     = (const float*)d_in[2];
    int* out = (int*)d_out;

    (void)hipFuncSetAttribute((const void*)crf_viterbi,
                              hipFuncAttributeMaxDynamicSharedMemorySize,
                              LDS_BYTES);

    crf_viterbi<<<NBATCH, 256, LDS_BYTES, stream>>>(emissions, mask, trans, out);
}